// Round 1
// baseline (92.622 us; speedup 1.0000x reference)
//
#include <hip/hip_runtime.h>
#include <hip/hip_bf16.h>

#define B_TOTAL 2048
#define IN_SZ   288
#define GH      64
#define E_NUM   8
#define OUT_N   256

__device__ __forceinline__ float elu_f(float x) {
    return x > 0.0f ? x : (expf(x) - 1.0f);
}

// ---------------- Gate MLP: one wave per sample row ----------------
__global__ __launch_bounds__(64) void gate_kernel(
    const float* __restrict__ z,
    const float* __restrict__ g0_w, const float* __restrict__ g0_b,
    const float* __restrict__ g1_w, const float* __restrict__ g1_b,
    const float* __restrict__ g2_w, const float* __restrict__ g2_b,
    float* __restrict__ coef)
{
    __shared__ float z_s[IN_SZ];
    __shared__ float h0_s[GH];
    __shared__ float h1_s[GH];
    const int b = blockIdx.x;
    const int t = threadIdx.x;
    const float* zr = z + (size_t)b * IN_SZ;
    for (int i = t; i < IN_SZ; i += 64) z_s[i] = zr[i];
    __syncthreads();

    // layer 0: [288]->[64], lane t computes column t (coalesced weight reads)
    float a0 = g0_b[t];
    #pragma unroll 4
    for (int i = 0; i < IN_SZ; ++i) a0 += z_s[i] * g0_w[i * GH + t];
    h0_s[t] = elu_f(a0);
    __syncthreads();

    // layer 1: [64]->[64]
    float a1 = g1_b[t];
    #pragma unroll 4
    for (int k = 0; k < GH; ++k) a1 += h0_s[k] * g1_w[k * GH + t];
    h1_s[t] = elu_f(a1);
    __syncthreads();

    // layer 2: [64]->[8] + softmax across lanes 0..7
    if (t < E_NUM) {
        float l = g2_b[t];
        #pragma unroll 4
        for (int k = 0; k < GH; ++k) l += h1_s[k] * g2_w[k * E_NUM + t];
        float m = l;
        for (int d = 1; d < 8; d <<= 1) m = fmaxf(m, __shfl_xor(m, d, 8));
        float ex = expf(l - m);
        float s = ex;
        for (int d = 1; d < 8; d <<= 1) s += __shfl_xor(s, d, 8);
        coef[b * E_NUM + t] = ex / s;
    }
}

// ---------------- Expert GEMM: y[e][b][o] = z[b,:] @ w2[e,:,o] ----------------
// grid (B/BM, E), block 256. Each thread owns one output column for BM rows.
#define BM 16
__global__ __launch_bounds__(256) void expert_kernel(
    const float* __restrict__ z, const float* __restrict__ w2,
    float* __restrict__ y)
{
    __shared__ float z_s[BM][IN_SZ];
    const int b0 = blockIdx.x * BM;
    const int e  = blockIdx.y;
    const int t  = threadIdx.x;

    for (int idx = t; idx < BM * IN_SZ; idx += 256) {
        ((float*)z_s)[idx] = z[(size_t)b0 * IN_SZ + idx];
    }
    __syncthreads();

    const float* w = w2 + (size_t)e * IN_SZ * OUT_N + t;
    float acc[BM];
    #pragma unroll
    for (int r = 0; r < BM; ++r) acc[r] = 0.0f;

    #pragma unroll 4
    for (int i = 0; i < IN_SZ; ++i) {
        float wv = w[i * OUT_N];           // coalesced, L2-resident
        #pragma unroll
        for (int r = 0; r < BM; ++r) acc[r] += z_s[r][i] * wv;  // LDS broadcast
    }

    float* yo = y + ((size_t)e * B_TOTAL + b0) * OUT_N + t;
    #pragma unroll
    for (int r = 0; r < BM; ++r) yo[(size_t)r * OUT_N] = acc[r];
}

// ---------------- Reduce: out[b,o] = sum_e coef[b,e]*(y[e,b,o] + b2[e,o]) ----------------
__global__ __launch_bounds__(256) void reduce_kernel(
    const float* __restrict__ y, const float* __restrict__ coef,
    const float* __restrict__ b2, float* __restrict__ out)
{
    const int idx = blockIdx.x * 256 + threadIdx.x;   // 0 .. B*OUT_N-1
    const int b = idx >> 8;
    const int o = idx & 255;
    float acc = 0.0f;
    #pragma unroll
    for (int e = 0; e < E_NUM; ++e) {
        float c = coef[b * E_NUM + e];
        acc += c * (y[((size_t)e * B_TOTAL + b) * OUT_N + o] + b2[e * OUT_N + o]);
    }
    out[idx] = acc;
}

// ---------------- Fallback (small ws): direct per-row-tile, loops all experts ----------------
__global__ __launch_bounds__(256) void direct_kernel(
    const float* __restrict__ z, const float* __restrict__ w2,
    const float* __restrict__ b2, const float* __restrict__ coef,
    float* __restrict__ out)
{
    __shared__ float z_s[8][IN_SZ];
    __shared__ float c_s[8][E_NUM];
    const int b0 = blockIdx.x * 8;
    const int t  = threadIdx.x;

    for (int idx = t; idx < 8 * IN_SZ; idx += 256)
        ((float*)z_s)[idx] = z[(size_t)b0 * IN_SZ + idx];
    if (t < 64) c_s[t >> 3][t & 7] = coef[b0 * E_NUM + t];
    __syncthreads();

    float outv[8];
    #pragma unroll
    for (int r = 0; r < 8; ++r) outv[r] = 0.0f;

    for (int e = 0; e < E_NUM; ++e) {
        const float* w = w2 + (size_t)e * IN_SZ * OUT_N + t;
        float tmp[8];
        #pragma unroll
        for (int r = 0; r < 8; ++r) tmp[r] = 0.0f;
        #pragma unroll 4
        for (int i = 0; i < IN_SZ; ++i) {
            float wv = w[i * OUT_N];
            #pragma unroll
            for (int r = 0; r < 8; ++r) tmp[r] += z_s[r][i] * wv;
        }
        float bv = b2[e * OUT_N + t];
        #pragma unroll
        for (int r = 0; r < 8; ++r) outv[r] += c_s[r][e] * (tmp[r] + bv);
    }
    #pragma unroll
    for (int r = 0; r < 8; ++r) out[(size_t)(b0 + r) * OUT_N + t] = outv[r];
}

extern "C" void kernel_launch(void* const* d_in, const int* in_sizes, int n_in,
                              void* d_out, int out_size, void* d_ws, size_t ws_size,
                              hipStream_t stream) {
    const float* z    = (const float*)d_in[0];
    const float* g0_w = (const float*)d_in[1];
    const float* g0_b = (const float*)d_in[2];
    const float* g1_w = (const float*)d_in[3];
    const float* g1_b = (const float*)d_in[4];
    const float* g2_w = (const float*)d_in[5];
    const float* g2_b = (const float*)d_in[6];
    // d_in[7..10] = w0,b0,w1,b1 are dead in the reference (layer_out never fed back)
    const float* w2   = (const float*)d_in[11];
    const float* b2   = (const float*)d_in[12];
    float* out = (float*)d_out;

    float* coef = (float*)d_ws;                         // B*8 floats = 64 KB
    const size_t coef_bytes = (size_t)B_TOTAL * E_NUM * sizeof(float);
    const size_t y_bytes    = (size_t)E_NUM * B_TOTAL * OUT_N * sizeof(float);

    gate_kernel<<<B_TOTAL, 64, 0, stream>>>(z, g0_w, g0_b, g1_w, g1_b, g2_w, g2_b, coef);

    if (ws_size >= coef_bytes + y_bytes) {
        float* y = (float*)((char*)d_ws + coef_bytes);
        expert_kernel<<<dim3(B_TOTAL / BM, E_NUM), 256, 0, stream>>>(z, w2, y);
        reduce_kernel<<<(B_TOTAL * OUT_N) / 256, 256, 0, stream>>>(y, coef, b2, out);
    } else {
        direct_kernel<<<B_TOTAL / 8, 256, 0, stream>>>(z, w2, b2, coef, out);
    }
}

// Round 2
// 47.701 us; speedup vs baseline: 1.9417x; 1.9417x over previous
//
#include <hip/hip_runtime.h>
#include <hip/hip_bf16.h>

#define B_TOTAL 2048
#define IN_SZ   288
#define GH      64
#define E_NUM   8
#define OUT_N   256
#define K_TOT   (E_NUM * IN_SZ)   // 2304

typedef __attribute__((ext_vector_type(8))) short bf16x8;
typedef __attribute__((ext_vector_type(4))) float f32x4;

__device__ __forceinline__ float elu_f(float x) {
    return x > 0.0f ? x : (expf(x) - 1.0f);
}
__device__ __forceinline__ ushort f2bf(float f) {
    __hip_bfloat16 h = __float2bfloat16(f);
    return *reinterpret_cast<ushort*>(&h);
}

// ---------------- Gate MLP: 4 rows/block, one wave per row ----------------
__global__ __launch_bounds__(256) void gate_kernel(
    const float* __restrict__ z,
    const float* __restrict__ g0_w, const float* __restrict__ g0_b,
    const float* __restrict__ g1_w, const float* __restrict__ g1_b,
    const float* __restrict__ g2_w, const float* __restrict__ g2_b,
    float* __restrict__ coef)
{
    __shared__ float z_s[4][IN_SZ];
    __shared__ float h0_s[4][GH];
    __shared__ float h1_s[4][GH];
    const int wid = threadIdx.x >> 6;
    const int l   = threadIdx.x & 63;
    const int b   = blockIdx.x * 4 + wid;

    const float4* zr = (const float4*)(z + (size_t)b * IN_SZ);
    float4 v = zr[l];
    *(float4*)&z_s[wid][l * 4] = v;                 // 64 lanes cover 256 elems
    if (l < 8) {                                    // remaining 32 elems
        float4 v2 = zr[64 + l];
        *(float4*)&z_s[wid][256 + l * 4] = v2;
    }
    __syncthreads();

    float a0 = g0_b[l];
    #pragma unroll 4
    for (int i = 0; i < IN_SZ; ++i) a0 = fmaf(z_s[wid][i], g0_w[i * GH + l], a0);
    h0_s[wid][l] = elu_f(a0);
    __syncthreads();

    float a1 = g1_b[l];
    #pragma unroll 4
    for (int k = 0; k < GH; ++k) a1 = fmaf(h0_s[wid][k], g1_w[k * GH + l], a1);
    h1_s[wid][l] = elu_f(a1);
    __syncthreads();

    // layer2 distributed: lane l -> expert l&7, k-slice l>>3
    const int e = l & 7, kk = l >> 3;
    float p = 0.f;
    #pragma unroll
    for (int j = 0; j < 8; ++j)
        p = fmaf(h1_s[wid][kk + 8 * j], g2_w[(kk + 8 * j) * E_NUM + e], p);
    p += __shfl_xor(p, 8);
    p += __shfl_xor(p, 16);
    p += __shfl_xor(p, 32);
    if (l < 8) {
        float logit = p + g2_b[e];
        float m = logit;
        m = fmaxf(m, __shfl_xor(m, 1));
        m = fmaxf(m, __shfl_xor(m, 2));
        m = fmaxf(m, __shfl_xor(m, 4));
        float ex = expf(logit - m);
        float s = ex;
        s += __shfl_xor(s, 1);
        s += __shfl_xor(s, 2);
        s += __shfl_xor(s, 4);
        coef[b * E_NUM + l] = ex / s;
    }
}

// ---------------- zc[b, e*288+i] = coef[b,e] * z[b,i]  (bf16) ----------------
__global__ __launch_bounds__(256) void prep_zc_kernel(
    const float* __restrict__ z, const float* __restrict__ coef,
    ushort* __restrict__ zc)
{
    __shared__ float z_s[2][IN_SZ];
    __shared__ float c_s[2][E_NUM];
    const int b0 = blockIdx.x * 2;
    const int t = threadIdx.x;
    if (t < 144) {
        float4 v = ((const float4*)(z + (size_t)b0 * IN_SZ))[t];
        *(float4*)&((float*)z_s)[t * 4] = v;
    }
    if (t < 16) ((float*)c_s)[t] = coef[b0 * E_NUM + t];
    __syncthreads();

    #pragma unroll 3
    for (int idx = t; idx < 2 * (K_TOT / 4); idx += 256) {   // 1152 quad-slots
        int r  = idx / (K_TOT / 4);
        int s4 = idx % (K_TOT / 4);
        int k4 = s4 * 4;
        int e  = k4 / IN_SZ;
        int i  = k4 - e * IN_SZ;
        float c = c_s[r][e];
        float4 zv = *(const float4*)&z_s[r][i];
        ushort4 o;
        o.x = f2bf(c * zv.x); o.y = f2bf(c * zv.y);
        o.z = f2bf(c * zv.z); o.w = f2bf(c * zv.w);
        *(ushort4*)&zc[(size_t)(b0 + r) * K_TOT + k4] = o;
    }
}

// ---------------- w2 [2304][256] f32  ->  w2t [256][2304] bf16 ----------------
__global__ __launch_bounds__(256) void wt_kernel(
    const float* __restrict__ w2, ushort* __restrict__ w2t)
{
    __shared__ float ts[32][33];
    const int k0 = blockIdx.x * 32;   // 72 blocks
    const int o0 = blockIdx.y * 32;   // 8 blocks
    const int t = threadIdx.x;
    #pragma unroll
    for (int idx = t; idx < 1024; idx += 256) {
        int r = idx >> 5, c = idx & 31;
        ts[r][c] = w2[(size_t)(k0 + r) * OUT_N + o0 + c];
    }
    __syncthreads();
    #pragma unroll
    for (int idx = t; idx < 1024; idx += 256) {
        int r = idx >> 5, c = idx & 31;   // r = o-offset, c = k-offset
        w2t[(size_t)(o0 + r) * K_TOT + k0 + c] = f2bf(ts[c][r]);
    }
}

// ---------------- GEMM: out = zc[2048x2304] @ w2t^T + coef@b2 ----------------
#define BMg 32
#define BNg 64
#define BKg 64
#define LDK 88            // 176B rows: 16B-aligned, bank-stagger via 44-dword stride
#define NKI (K_TOT / BKg) // 36

__global__ __launch_bounds__(256) void gemm_kernel(
    const ushort* __restrict__ zc, const ushort* __restrict__ w2t,
    const float* __restrict__ coef, const float* __restrict__ b2,
    float* __restrict__ out)
{
    __shared__ ushort As[BMg][LDK];
    __shared__ ushort Bs[BNg][LDK];
    __shared__ float  c_s[BMg][E_NUM];

    const int t   = threadIdx.x;
    const int wid = t >> 6, l = t & 63;
    const int m0 = blockIdx.x * BMg;
    const int n0 = blockIdx.y * BNg;

    ((float*)c_s)[t] = coef[m0 * E_NUM + t];   // 32*8 = 256 floats

    // staging: thread t owns 16B chunk (row t>>3, kchunk t&7) of A, rows t>>3 and 32+(t>>3) of B
    const int ar = t >> 3;
    const int ac = (t & 7) * 8;
    const ushort* gA  = zc  + (size_t)(m0 + ar) * K_TOT + ac;
    const ushort* gB0 = w2t + (size_t)(n0 + ar) * K_TOT + ac;
    const ushort* gB1 = w2t + (size_t)(n0 + 32 + ar) * K_TOT + ac;

    int4 ra  = *(const int4*)gA;
    int4 rb0 = *(const int4*)gB0;
    int4 rb1 = *(const int4*)gB1;

    const int mt  = wid & 1;            // m-tile of this wave
    const int nt0 = (wid >> 1) * 2;     // first of two n-tiles

    f32x4 acc0 = {0.f, 0.f, 0.f, 0.f};
    f32x4 acc1 = {0.f, 0.f, 0.f, 0.f};

    const int frow = l & 15, fk = (l >> 4) * 8;
    const ushort* aRd  = &As[mt * 16 + frow][fk];
    const ushort* bRd0 = &Bs[nt0 * 16 + frow][fk];
    const ushort* bRd1 = &Bs[(nt0 + 1) * 16 + frow][fk];

    for (int ki = 0; ki < NKI; ++ki) {
        *(int4*)&As[ar][ac] = ra;
        *(int4*)&Bs[ar][ac] = rb0;
        *(int4*)&Bs[32 + ar][ac] = rb1;
        __syncthreads();
        if (ki + 1 < NKI) {
            gA += BKg; gB0 += BKg; gB1 += BKg;
            ra  = *(const int4*)gA;
            rb0 = *(const int4*)gB0;
            rb1 = *(const int4*)gB1;
        }
        bf16x8 a0  = *(const bf16x8*)aRd;
        bf16x8 a1  = *(const bf16x8*)(aRd + 32);
        bf16x8 b00 = *(const bf16x8*)bRd0;
        bf16x8 b01 = *(const bf16x8*)(bRd0 + 32);
        bf16x8 b10 = *(const bf16x8*)bRd1;
        bf16x8 b11 = *(const bf16x8*)(bRd1 + 32);
        acc0 = __builtin_amdgcn_mfma_f32_16x16x32_bf16(a0, b00, acc0, 0, 0, 0);
        acc1 = __builtin_amdgcn_mfma_f32_16x16x32_bf16(a0, b10, acc1, 0, 0, 0);
        acc0 = __builtin_amdgcn_mfma_f32_16x16x32_bf16(a1, b01, acc0, 0, 0, 0);
        acc1 = __builtin_amdgcn_mfma_f32_16x16x32_bf16(a1, b11, acc1, 0, 0, 0);
        __syncthreads();
    }

    // epilogue: + sum_e coef[b,e]*b2[e,o], fp32
    const int col0 = n0 + nt0 * 16 + frow;
    const int col1 = col0 + 16;
    #pragma unroll
    for (int j = 0; j < 4; ++j) {
        int rloc = mt * 16 + (l >> 4) * 4 + j;
        int row = m0 + rloc;
        float bias0 = 0.f, bias1 = 0.f;
        #pragma unroll
        for (int e = 0; e < E_NUM; ++e) {
            float c = c_s[rloc][e];
            bias0 = fmaf(c, b2[e * OUT_N + col0], bias0);
            bias1 = fmaf(c, b2[e * OUT_N + col1], bias1);
        }
        out[(size_t)row * OUT_N + col0] = acc0[j] + bias0;
        out[(size_t)row * OUT_N + col1] = acc1[j] + bias1;
    }
}

// ---------------- Fallback (small ws): direct fp32 path ----------------
__global__ __launch_bounds__(256) void direct_kernel(
    const float* __restrict__ z, const float* __restrict__ w2,
    const float* __restrict__ b2, const float* __restrict__ coef,
    float* __restrict__ out)
{
    __shared__ float z_s[8][IN_SZ];
    __shared__ float c_s[8][E_NUM];
    const int b0 = blockIdx.x * 8;
    const int t  = threadIdx.x;

    for (int idx = t; idx < 8 * IN_SZ; idx += 256)
        ((float*)z_s)[idx] = z[(size_t)b0 * IN_SZ + idx];
    if (t < 64) c_s[t >> 3][t & 7] = coef[b0 * E_NUM + t];
    __syncthreads();

    float outv[8];
    #pragma unroll
    for (int r = 0; r < 8; ++r) outv[r] = 0.0f;

    for (int e = 0; e < E_NUM; ++e) {
        const float* w = w2 + (size_t)e * IN_SZ * OUT_N + t;
        float tmp[8];
        #pragma unroll
        for (int r = 0; r < 8; ++r) tmp[r] = 0.0f;
        #pragma unroll 4
        for (int i = 0; i < IN_SZ; ++i) {
            float wv = w[i * OUT_N];
            #pragma unroll
            for (int r = 0; r < 8; ++r) tmp[r] += z_s[r][i] * wv;
        }
        float bv = b2[e * OUT_N + t];
        #pragma unroll
        for (int r = 0; r < 8; ++r) outv[r] += c_s[r][e] * (tmp[r] + bv);
    }
    #pragma unroll
    for (int r = 0; r < 8; ++r) out[(size_t)(b0 + r) * OUT_N + t] = outv[r];
}

extern "C" void kernel_launch(void* const* d_in, const int* in_sizes, int n_in,
                              void* d_out, int out_size, void* d_ws, size_t ws_size,
                              hipStream_t stream) {
    const float* z    = (const float*)d_in[0];
    const float* g0_w = (const float*)d_in[1];
    const float* g0_b = (const float*)d_in[2];
    const float* g1_w = (const float*)d_in[3];
    const float* g1_b = (const float*)d_in[4];
    const float* g2_w = (const float*)d_in[5];
    const float* g2_b = (const float*)d_in[6];
    // d_in[7..10] = w0,b0,w1,b1 are dead in the reference (layer_out never fed back)
    const float* w2   = (const float*)d_in[11];
    const float* b2   = (const float*)d_in[12];
    float* out = (float*)d_out;

    const size_t coef_bytes = (size_t)B_TOTAL * E_NUM * sizeof(float);       // 64 KB
    const size_t zc_bytes   = (size_t)B_TOTAL * K_TOT * sizeof(ushort);      // 9.44 MB
    const size_t wt_bytes   = (size_t)OUT_N * K_TOT * sizeof(ushort);        // 1.18 MB

    float* coef = (float*)d_ws;

    gate_kernel<<<B_TOTAL / 4, 256, 0, stream>>>(z, g0_w, g0_b, g1_w, g1_b, g2_w, g2_b, coef);

    if (ws_size >= coef_bytes + zc_bytes + wt_bytes) {
        ushort* zc  = (ushort*)((char*)d_ws + coef_bytes);
        ushort* w2t = (ushort*)((char*)d_ws + coef_bytes + zc_bytes);
        prep_zc_kernel<<<B_TOTAL / 2, 256, 0, stream>>>(z, coef, zc);
        wt_kernel<<<dim3(K_TOT / 32, OUT_N / 32), 256, 0, stream>>>(w2, w2t);
        gemm_kernel<<<dim3(B_TOTAL / BMg, OUT_N / BNg), 256, 0, stream>>>(zc, w2t, coef, b2, out);
    } else {
        direct_kernel<<<B_TOTAL / 8, 256, 0, stream>>>(z, w2, b2, coef, out);
    }
}

// Round 3
// 41.183 us; speedup vs baseline: 2.2490x; 1.1583x over previous
//
#include <hip/hip_runtime.h>
#include <hip/hip_bf16.h>

#define B_TOTAL 2048
#define IN_SZ   288
#define GH      64
#define E_NUM   8
#define OUT_N   256
#define K_TOT   (E_NUM * IN_SZ)   // 2304

#define GATE_ROWS   8
#define GATE_BLOCKS (B_TOTAL / GATE_ROWS)  // 256
#define WT_BLOCKS   (K_TOT / 32)           // 72

typedef __attribute__((ext_vector_type(8))) short bf16x8;
typedef __attribute__((ext_vector_type(4))) float f32x4;

__device__ __forceinline__ float elu_f(float x) {
    return x > 0.0f ? x : (expf(x) - 1.0f);
}
__device__ __forceinline__ ushort f2bf(float f) {
    __hip_bfloat16 h = __float2bfloat16(f);
    return *reinterpret_cast<ushort*>(&h);
}
__device__ __forceinline__ float bf2f(ushort u) {
    union { unsigned int u; float f; } v;
    v.u = ((unsigned int)u) << 16;
    return v.f;
}
__device__ __forceinline__ unsigned int pack2(float a, float b) {
    return (unsigned int)f2bf(a) | ((unsigned int)f2bf(b) << 16);
}

// ============ Fused: gate MLP (f32 act, bf16 wts in LDS) + zc build + w2 transpose ============
// Blocks [0, GATE_BLOCKS): 8 rows each -> coef + zc rows.
// Blocks [GATE_BLOCKS, GATE_BLOCKS+WT_BLOCKS): transpose a 32-k slab of w2 -> w2t bf16.
__global__ __launch_bounds__(256) void fused_prep_kernel(
    const float* __restrict__ z,
    const float* __restrict__ g0_w, const float* __restrict__ g0_b,
    const float* __restrict__ g1_w, const float* __restrict__ g1_b,
    const float* __restrict__ g2_w, const float* __restrict__ g2_b,
    const float* __restrict__ w2,
    float* __restrict__ coef, ushort* __restrict__ zc, ushort* __restrict__ w2t,
    int write_zc)
{
    __shared__ char smem[60192];
    const int t = threadIdx.x;

    if (blockIdx.x >= GATE_BLOCKS) {
        // ---- w2 [2304][256] f32 -> w2t [256][2304] bf16, one 32-k slab ----
        float (*ts)[33] = (float(*)[33])smem;
        const int k0 = (blockIdx.x - GATE_BLOCKS) * 32;
        for (int og = 0; og < 8; ++og) {
            const int o0 = og * 32;
            __syncthreads();
            #pragma unroll
            for (int idx = t; idx < 1024; idx += 256) {
                int r = idx >> 5, c = idx & 31;
                ts[r][c] = w2[(size_t)(k0 + r) * OUT_N + o0 + c];
            }
            __syncthreads();
            #pragma unroll
            for (int idx = t; idx < 1024; idx += 256) {
                int r = idx >> 5, c = idx & 31;   // r = o-off, c = k-off
                w2t[(size_t)(o0 + r) * K_TOT + k0 + c] = f2bf(ts[c][r]);
            }
        }
        return;
    }

    // ---- LDS carve (total 60192 B) ----
    ushort* w0s = (ushort*)smem;               // [288*64] bf16  36864 B
    ushort* w1s = (ushort*)(smem + 36864);     // [64*64]        8192 B
    ushort* w2s = (ushort*)(smem + 45056);     // [64*8]         1024 B
    float*  b0s = (float*)(smem + 46080);      // 64
    float*  b1s = (float*)(smem + 46336);      // 64
    float*  b2s = (float*)(smem + 46592);      // 8
    float*  z_s = (float*)(smem + 46624);      // [8][288] f32   9216 B
    float*  h0s = (float*)(smem + 55840);      // [8][64]        2048 B
    float*  h1s = (float*)(smem + 57888);      // [8][64]        2048 B
    float*  c_s = (float*)(smem + 59936);      // [8][8]         256 B

    const int r0g = blockIdx.x * GATE_ROWS;

    // ---- stage weights (f32 -> bf16) + biases + z rows ----
    #pragma unroll 2
    for (int idx = t; idx < 4608; idx += 256) {           // g0_w: 18 iters
        float4 v = ((const float4*)g0_w)[idx];
        ushort4 o; o.x = f2bf(v.x); o.y = f2bf(v.y); o.z = f2bf(v.z); o.w = f2bf(v.w);
        *(ushort4*)&w0s[idx * 4] = o;
    }
    #pragma unroll
    for (int idx = t; idx < 1024; idx += 256) {           // g1_w: 4 iters
        float4 v = ((const float4*)g1_w)[idx];
        ushort4 o; o.x = f2bf(v.x); o.y = f2bf(v.y); o.z = f2bf(v.z); o.w = f2bf(v.w);
        *(ushort4*)&w1s[idx * 4] = o;
    }
    if (t < 128) {                                        // g2_w: 512 floats
        float4 v = ((const float4*)g2_w)[t];
        ushort4 o; o.x = f2bf(v.x); o.y = f2bf(v.y); o.z = f2bf(v.z); o.w = f2bf(v.w);
        *(ushort4*)&w2s[t * 4] = o;
    }
    if (t < 16)              ((float4*)b0s)[t]      = ((const float4*)g0_b)[t];
    if (t >= 16 && t < 32)   ((float4*)b1s)[t - 16] = ((const float4*)g1_b)[t - 16];
    if (t >= 32 && t < 34)   ((float4*)b2s)[t - 32] = ((const float4*)g2_b)[t - 32];
    #pragma unroll
    for (int idx = t; idx < (GATE_ROWS * IN_SZ) / 4; idx += 256) {   // z: 576 f4
        ((float4*)z_s)[idx] = ((const float4*)(z + (size_t)r0g * IN_SZ))[idx];
    }
    __syncthreads();

    // ---- layer 0: [288]->[64]; wave wid handles rows 2wid, 2wid+1; lane = out col ----
    const int wid = t >> 6, l = t & 63;
    const int ra = wid * 2, rb = wid * 2 + 1;
    float a0 = b0s[l], a1 = b0s[l];
    #pragma unroll 4
    for (int k = 0; k < IN_SZ; ++k) {
        float wv = bf2f(w0s[k * 64 + l]);
        a0 = fmaf(z_s[ra * IN_SZ + k], wv, a0);
        a1 = fmaf(z_s[rb * IN_SZ + k], wv, a1);
    }
    h0s[ra * 64 + l] = elu_f(a0);
    h0s[rb * 64 + l] = elu_f(a1);
    __syncthreads();

    // ---- layer 1: [64]->[64] ----
    a0 = b1s[l]; a1 = b1s[l];
    #pragma unroll 4
    for (int k = 0; k < GH; ++k) {
        float wv = bf2f(w1s[k * 64 + l]);
        a0 = fmaf(h0s[ra * 64 + k], wv, a0);
        a1 = fmaf(h0s[rb * 64 + k], wv, a1);
    }
    h1s[ra * 64 + l] = elu_f(a0);
    h1s[rb * 64 + l] = elu_f(a1);
    __syncthreads();

    // ---- layer 2 + softmax: thread t<64 -> (row t>>3, expert t&7) ----
    if (t < 64) {
        const int r = t >> 3, e = t & 7;
        float acc = b2s[e];
        #pragma unroll 4
        for (int k = 0; k < GH; ++k)
            acc = fmaf(h1s[r * 64 + k], bf2f(w2s[k * 8 + e]), acc);
        float m = acc;
        m = fmaxf(m, __shfl_xor(m, 1));
        m = fmaxf(m, __shfl_xor(m, 2));
        m = fmaxf(m, __shfl_xor(m, 4));
        float ex = expf(acc - m);
        float s = ex;
        s += __shfl_xor(s, 1);
        s += __shfl_xor(s, 2);
        s += __shfl_xor(s, 4);
        float c = ex / s;
        c_s[t] = c;
        coef[(r0g + r) * E_NUM + e] = c;
    }
    __syncthreads();

    // ---- zc[b, e*288+i] = coef[b,e] * z[b,i] (bf16), 16B stores ----
    if (write_zc) {
        #pragma unroll 3
        for (int idx = t; idx < GATE_ROWS * (K_TOT / 8); idx += 256) {  // 2304
            int row = idx / (K_TOT / 8);
            int s8  = idx - row * (K_TOT / 8);
            int k8  = s8 * 8;
            int e   = k8 / IN_SZ;
            int i   = k8 - e * IN_SZ;
            float c = c_s[row * E_NUM + e];
            const float* zp = &z_s[row * IN_SZ + i];
            float4 v0 = *(const float4*)zp;
            float4 v1 = *(const float4*)(zp + 4);
            int4 q;
            q.x = (int)pack2(c * v0.x, c * v0.y);
            q.y = (int)pack2(c * v0.z, c * v0.w);
            q.z = (int)pack2(c * v1.x, c * v1.y);
            q.w = (int)pack2(c * v1.z, c * v1.w);
            *(int4*)&zc[(size_t)(r0g + row) * K_TOT + k8] = q;
        }
    }
}

// ============ GEMM: out = zc[2048x2304] @ w2t^T + coef@b2 (unchanged from r2) ============
#define BMg 32
#define BNg 64
#define BKg 64
#define LDK 88
#define NKI (K_TOT / BKg) // 36

__global__ __launch_bounds__(256) void gemm_kernel(
    const ushort* __restrict__ zc, const ushort* __restrict__ w2t,
    const float* __restrict__ coef, const float* __restrict__ b2,
    float* __restrict__ out)
{
    __shared__ ushort As[BMg][LDK];
    __shared__ ushort Bs[BNg][LDK];
    __shared__ float  c_s[BMg][E_NUM];

    const int t   = threadIdx.x;
    const int wid = t >> 6, l = t & 63;
    const int m0 = blockIdx.x * BMg;
    const int n0 = blockIdx.y * BNg;

    ((float*)c_s)[t] = coef[m0 * E_NUM + t];

    const int ar = t >> 3;
    const int ac = (t & 7) * 8;
    const ushort* gA  = zc  + (size_t)(m0 + ar) * K_TOT + ac;
    const ushort* gB0 = w2t + (size_t)(n0 + ar) * K_TOT + ac;
    const ushort* gB1 = w2t + (size_t)(n0 + 32 + ar) * K_TOT + ac;

    int4 ra  = *(const int4*)gA;
    int4 rb0 = *(const int4*)gB0;
    int4 rb1 = *(const int4*)gB1;

    const int mt  = wid & 1;
    const int nt0 = (wid >> 1) * 2;

    f32x4 acc0 = {0.f, 0.f, 0.f, 0.f};
    f32x4 acc1 = {0.f, 0.f, 0.f, 0.f};

    const int frow = l & 15, fk = (l >> 4) * 8;
    const ushort* aRd  = &As[mt * 16 + frow][fk];
    const ushort* bRd0 = &Bs[nt0 * 16 + frow][fk];
    const ushort* bRd1 = &Bs[(nt0 + 1) * 16 + frow][fk];

    for (int ki = 0; ki < NKI; ++ki) {
        *(int4*)&As[ar][ac] = ra;
        *(int4*)&Bs[ar][ac] = rb0;
        *(int4*)&Bs[32 + ar][ac] = rb1;
        __syncthreads();
        if (ki + 1 < NKI) {
            gA += BKg; gB0 += BKg; gB1 += BKg;
            ra  = *(const int4*)gA;
            rb0 = *(const int4*)gB0;
            rb1 = *(const int4*)gB1;
        }
        bf16x8 a0  = *(const bf16x8*)aRd;
        bf16x8 a1  = *(const bf16x8*)(aRd + 32);
        bf16x8 b00 = *(const bf16x8*)bRd0;
        bf16x8 b01 = *(const bf16x8*)(bRd0 + 32);
        bf16x8 b10 = *(const bf16x8*)bRd1;
        bf16x8 b11 = *(const bf16x8*)(bRd1 + 32);
        acc0 = __builtin_amdgcn_mfma_f32_16x16x32_bf16(a0, b00, acc0, 0, 0, 0);
        acc1 = __builtin_amdgcn_mfma_f32_16x16x32_bf16(a0, b10, acc1, 0, 0, 0);
        acc0 = __builtin_amdgcn_mfma_f32_16x16x32_bf16(a1, b01, acc0, 0, 0, 0);
        acc1 = __builtin_amdgcn_mfma_f32_16x16x32_bf16(a1, b11, acc1, 0, 0, 0);
        __syncthreads();
    }

    const int col0 = n0 + nt0 * 16 + frow;
    const int col1 = col0 + 16;
    #pragma unroll
    for (int j = 0; j < 4; ++j) {
        int rloc = mt * 16 + (l >> 4) * 4 + j;
        int row = m0 + rloc;
        float bias0 = 0.f, bias1 = 0.f;
        #pragma unroll
        for (int e = 0; e < E_NUM; ++e) {
            float c = c_s[rloc][e];
            bias0 = fmaf(c, b2[e * OUT_N + col0], bias0);
            bias1 = fmaf(c, b2[e * OUT_N + col1], bias1);
        }
        out[(size_t)row * OUT_N + col0] = acc0[j] + bias0;
        out[(size_t)row * OUT_N + col1] = acc1[j] + bias1;
    }
}

// ============ Fallback (small ws): direct fp32 path ============
__global__ __launch_bounds__(256) void direct_kernel(
    const float* __restrict__ z, const float* __restrict__ w2,
    const float* __restrict__ b2, const float* __restrict__ coef,
    float* __restrict__ out)
{
    __shared__ float z_s[8][IN_SZ];
    __shared__ float c_s[8][E_NUM];
    const int b0 = blockIdx.x * 8;
    const int t  = threadIdx.x;

    for (int idx = t; idx < 8 * IN_SZ; idx += 256)
        ((float*)z_s)[idx] = z[(size_t)b0 * IN_SZ + idx];
    if (t < 64) c_s[t >> 3][t & 7] = coef[b0 * E_NUM + t];
    __syncthreads();

    float outv[8];
    #pragma unroll
    for (int r = 0; r < 8; ++r) outv[r] = 0.0f;

    for (int e = 0; e < E_NUM; ++e) {
        const float* w = w2 + (size_t)e * IN_SZ * OUT_N + t;
        float tmp[8];
        #pragma unroll
        for (int r = 0; r < 8; ++r) tmp[r] = 0.0f;
        #pragma unroll 4
        for (int i = 0; i < IN_SZ; ++i) {
            float wv = w[i * OUT_N];
            #pragma unroll
            for (int r = 0; r < 8; ++r) tmp[r] += z_s[r][i] * wv;
        }
        float bv = b2[e * OUT_N + t];
        #pragma unroll
        for (int r = 0; r < 8; ++r) outv[r] += c_s[r][e] * (tmp[r] + bv);
    }
    #pragma unroll
    for (int r = 0; r < 8; ++r) out[(size_t)(b0 + r) * OUT_N + t] = outv[r];
}

extern "C" void kernel_launch(void* const* d_in, const int* in_sizes, int n_in,
                              void* d_out, int out_size, void* d_ws, size_t ws_size,
                              hipStream_t stream) {
    const float* z    = (const float*)d_in[0];
    const float* g0_w = (const float*)d_in[1];
    const float* g0_b = (const float*)d_in[2];
    const float* g1_w = (const float*)d_in[3];
    const float* g1_b = (const float*)d_in[4];
    const float* g2_w = (const float*)d_in[5];
    const float* g2_b = (const float*)d_in[6];
    // d_in[7..10] = w0,b0,w1,b1 are dead in the reference (layer_out never fed back)
    const float* w2   = (const float*)d_in[11];
    const float* b2   = (const float*)d_in[12];
    float* out = (float*)d_out;

    const size_t coef_bytes = (size_t)B_TOTAL * E_NUM * sizeof(float);       // 64 KB
    const size_t zc_bytes   = (size_t)B_TOTAL * K_TOT * sizeof(ushort);      // 9.44 MB
    const size_t wt_bytes   = (size_t)OUT_N * K_TOT * sizeof(ushort);        // 1.18 MB

    float*  coef = (float*)d_ws;
    ushort* zc   = (ushort*)((char*)d_ws + coef_bytes);
    ushort* w2t  = (ushort*)((char*)d_ws + coef_bytes + zc_bytes);

    if (ws_size >= coef_bytes + zc_bytes + wt_bytes) {
        fused_prep_kernel<<<GATE_BLOCKS + WT_BLOCKS, 256, 0, stream>>>(
            z, g0_w, g0_b, g1_w, g1_b, g2_w, g2_b, w2, coef, zc, w2t, 1);
        gemm_kernel<<<dim3(B_TOTAL / BMg, OUT_N / BNg), 256, 0, stream>>>(
            zc, w2t, coef, b2, out);
    } else {
        fused_prep_kernel<<<GATE_BLOCKS, 256, 0, stream>>>(
            z, g0_w, g0_b, g1_w, g1_b, g2_w, g2_b, w2, coef, zc, w2t, 0);
        direct_kernel<<<B_TOTAL / 8, 256, 0, stream>>>(z, w2, b2, coef, out);
    }
}